// Round 1
// baseline (175.858 us; speedup 1.0000x reference)
//
#include <hip/hip_runtime.h>
#include <hip/hip_bf16.h>
#include <math.h>

// Problem constants
#define B_ 8
#define C_ 64
#define H_ 256
#define W_ 256
#define HL_ 128
#define WL_ 128
#define GN_G 8        // groupnorm groups
#define CPG 8         // channels per GN group
#define GRP 4         // sampling groups
#define OC_ 8
#define PB 16         // partial blocks per GN group
#define GROUP_ELEMS (CPG * H_ * W_)   // 524288

// ---------------- Kernel 1: partial GN stats ----------------
// grid: 64 groups * PB blocks, 256 threads
__global__ __launch_bounds__(256) void k1_partial(const float* __restrict__ x,
                                                  float* __restrict__ partials) {
  const int gi = blockIdx.x / PB;     // (b*8+g)
  const int part = blockIdx.x % PB;
  const float* base = x + (size_t)gi * GROUP_ELEMS + (size_t)part * (GROUP_ELEMS / PB);
  const int t = threadIdx.x;
  float s = 0.f, s2 = 0.f;
#pragma unroll
  for (int i = 0; i < 32; ++i) {
    const float4 v = *reinterpret_cast<const float4*>(base + (size_t)(i * 256 + t) * 4);
    s += v.x + v.y + v.z + v.w;
    s2 += v.x * v.x + v.y * v.y + v.z * v.z + v.w * v.w;
  }
#pragma unroll
  for (int off = 32; off > 0; off >>= 1) {
    s += __shfl_down(s, off, 64);
    s2 += __shfl_down(s2, off, 64);
  }
  __shared__ float ls[4], ls2[4];
  const int wid = t >> 6, lane = t & 63;
  if (lane == 0) { ls[wid] = s; ls2[wid] = s2; }
  __syncthreads();
  if (t == 0) {
    float S = 0.f, S2 = 0.f;
#pragma unroll
    for (int w = 0; w < 4; ++w) { S += ls[w]; S2 += ls2[w]; }
    partials[blockIdx.x * 2 + 0] = S;
    partials[blockIdx.x * 2 + 1] = S2;
  }
}

// ---------------- Kernel 1b: finalize per-(b,c) affine ----------------
// 1 block, 512 threads: t = b*64+c
__global__ __launch_bounds__(512) void k1_finish(const float* __restrict__ partials,
                                                 const float* __restrict__ gamma,
                                                 const float* __restrict__ beta,
                                                 float* __restrict__ ab) {
  const int t = threadIdx.x;
  const int b = t >> 6, c = t & 63, g = c >> 3;
  const int gi = b * GN_G + g;
  float S = 0.f, S2 = 0.f;
#pragma unroll
  for (int p = 0; p < PB; ++p) {
    S += partials[(gi * PB + p) * 2 + 0];
    S2 += partials[(gi * PB + p) * 2 + 1];
  }
  const float N = (float)GROUP_ELEMS;
  const float mean = S / N;
  const float var = fmaxf(S2 / N - mean * mean, 0.f);
  const float inv = rsqrtf(var + 1e-5f);
  const float ga = gamma[c];
  ab[t * 2 + 0] = inv * ga;
  ab[t * 2 + 1] = beta[c] - mean * inv * ga;
}

// ---------------- Kernel 2: fused GN + dwconv3 + avgpool2 ----------------
// thread per (b,c,hl,wl); writes xl, hfl in NCHW low-res
__global__ __launch_bounds__(256) void k2_pool(const float* __restrict__ x,
                                               const float* __restrict__ ab,
                                               const float* __restrict__ hpw,
                                               float* __restrict__ xl,
                                               float* __restrict__ hfl) {
  const int idx = blockIdx.x * 256 + threadIdx.x;
  const int wl = idx & (WL_ - 1);
  const int hl = (idx >> 7) & (HL_ - 1);
  const int bc = idx >> 14;            // b*64+c
  const int c = bc & 63;
  const float a = ab[bc * 2 + 0];
  const float bb = ab[bc * 2 + 1];
  float w[9];
#pragma unroll
  for (int i = 0; i < 9; ++i) w[i] = hpw[c * 9 + i];   // wave-uniform (c uniform in wave)
  const float* plane = x + (size_t)bc * (H_ * W_);
  float n[4][4];
#pragma unroll
  for (int dy = 0; dy < 4; ++dy) {
    const int y = 2 * hl - 1 + dy;
    const bool rok = ((unsigned)y < (unsigned)H_);
#pragma unroll
    for (int dx = 0; dx < 4; ++dx) {
      const int xx = 2 * wl - 1 + dx;
      const bool ok = rok && ((unsigned)xx < (unsigned)W_);
      n[dy][dx] = ok ? fmaf(a, plane[y * W_ + xx], bb) : 0.f;   // zero-padded xn
    }
  }
  float hfsum = 0.f;
#pragma unroll
  for (int r = 0; r < 2; ++r) {
#pragma unroll
    for (int s = 0; s < 2; ++s) {
      float h = 0.f;
#pragma unroll
      for (int i = 0; i < 3; ++i)
#pragma unroll
        for (int j = 0; j < 3; ++j)
          h = fmaf(w[i * 3 + j], n[r + i][s + j], h);
      hfsum += h;
    }
  }
  xl[idx] = 0.25f * (n[1][1] + n[1][2] + n[2][1] + n[2][2]);
  hfl[idx] = 0.25f * hfsum;
}

// ---------------- Kernel 3: direction feat + gates + offsets -> sample grid ----------------
// thread per low-res pixel (b,hl,wl)
__global__ __launch_bounds__(256) void k3_offset(const float* __restrict__ xl,
                                                 const float* __restrict__ hfl,
                                                 const float* __restrict__ dir_w,
                                                 const float* __restrict__ dir_b,
                                                 const float* __restrict__ mag_w,
                                                 const float* __restrict__ mag_b,
                                                 const float* __restrict__ hfg_w,
                                                 const float* __restrict__ hfg_b,
                                                 float2* __restrict__ grid) {
  __shared__ float s_mag[OC_ * C_], s_hfg[OC_ * C_], s_dir[OC_ * 8], s_b[3 * OC_];
  const int tid = threadIdx.x;
  for (int i = tid; i < OC_ * C_; i += 256) { s_mag[i] = mag_w[i]; s_hfg[i] = hfg_w[i]; }
  if (tid < OC_ * 8) s_dir[tid] = dir_w[tid];
  if (tid < OC_) { s_b[tid] = mag_b[tid]; s_b[OC_ + tid] = hfg_b[tid]; s_b[2 * OC_ + tid] = dir_b[tid]; }
  __syncthreads();

  const int idx = blockIdx.x * 256 + tid;   // B*HL*WL = 131072
  const int wl = idx & (WL_ - 1);
  const int hl = (idx >> 7) & (HL_ - 1);
  const int b = idx >> 14;

  float dot[9], n2[9];
#pragma unroll
  for (int k = 0; k < 9; ++k) { dot[k] = 0.f; n2[k] = 0.f; }
  float n1 = 0.f;
  float mago[OC_], hfgo[OC_];
#pragma unroll
  for (int o = 0; o < OC_; ++o) { mago[o] = 0.f; hfgo[o] = 0.f; }

  const int pbase = ((b * C_) * HL_ + hl) * WL_ + wl;
  for (int c = 0; c < C_; ++c) {
    const float* p = xl + pbase + c * (HL_ * WL_);
    const float vc = p[0];
    n1 = fmaf(vc, vc, n1);
#pragma unroll
    for (int k = 0; k < 9; ++k) {
      if (k == 4) continue;
      const int di = k / 3 - 1, dj = k % 3 - 1;
      const int y = hl + di, xx = wl + dj;
      const float v = (((unsigned)y < (unsigned)HL_) && ((unsigned)xx < (unsigned)WL_))
                          ? p[di * WL_ + dj] : 0.f;
      dot[k] = fmaf(vc, v, dot[k]);
      n2[k] = fmaf(v, v, n2[k]);
    }
    const float vh = hfl[pbase + c * (HL_ * WL_)];
#pragma unroll
    for (int o = 0; o < OC_; ++o) {
      mago[o] = fmaf(s_mag[o * C_ + c], vc, mago[o]);
      hfgo[o] = fmaf(s_hfg[o * C_ + c], vh, hfgo[o]);
    }
  }

  const float n1c = fmaxf(sqrtf(n1), 1e-8f);
  float df[8];
#pragma unroll
  for (int k = 0; k < 9; ++k) {
    if (k == 4) continue;
    const int j = (k < 4) ? k : k - 1;
    df[j] = dot[k] / (n1c * fmaxf(sqrtf(n2[k]), 1e-8f));
  }

  float off[OC_];
#pragma unroll
  for (int o = 0; o < OC_; ++o) {
    float t1 = s_b[2 * OC_ + o];
#pragma unroll
    for (int j = 0; j < 8; ++j) t1 = fmaf(s_dir[o * 8 + j], df[j], t1);
    const float z = mago[o] + s_b[o] + hfgo[o] + s_b[OC_ + o];
    const float gate = 1.f / (1.f + expf(-z));
    off[o] = t1 * gate;
  }

#pragma unroll
  for (int g = 0; g < GRP; ++g) {
    const float ix = fminf(fmaxf(2.f * wl + 0.5f + off[g], 0.f), (float)(W_ - 1));
    const float iy = fminf(fmaxf(2.f * hl + 0.5f + off[GRP + g], 0.f), (float)(H_ - 1));
    grid[((b * GRP + g) * (HL_ * WL_)) + hl * WL_ + wl] = make_float2(ix, iy);
  }
}

// ---------------- Kernel 4: bilinear grid sample (border) ----------------
// thread per output element (b,c,hl,wl)
__global__ __launch_bounds__(256) void k4_sample(const float* __restrict__ x,
                                                 const float2* __restrict__ grid,
                                                 float* __restrict__ out) {
  const int idx = blockIdx.x * 256 + threadIdx.x;
  const int wl = idx & (WL_ - 1);
  const int hl = (idx >> 7) & (HL_ - 1);
  const int bc = idx >> 14;
  const int c = bc & 63;
  const int b = bc >> 6;
  const int g = c >> 4;
  const float2 G = grid[(b * GRP + g) * (HL_ * WL_) + hl * WL_ + wl];
  const float ix = G.x, iy = G.y;
  const float x0f = floorf(ix), y0f = floorf(iy);
  const float wx = ix - x0f, wy = iy - y0f;
  const int x0 = (int)x0f, y0 = (int)y0f;
  const int x1 = min(x0 + 1, W_ - 1), y1 = min(y0 + 1, H_ - 1);
  const float* plane = x + (size_t)bc * (H_ * W_);
  const float v00 = plane[y0 * W_ + x0];
  const float v01 = plane[y0 * W_ + x1];
  const float v10 = plane[y1 * W_ + x0];
  const float v11 = plane[y1 * W_ + x1];
  out[idx] = v00 * (1.f - wx) * (1.f - wy) + v01 * wx * (1.f - wy)
           + v10 * (1.f - wx) * wy + v11 * wx * wy;
}

extern "C" void kernel_launch(void* const* d_in, const int* in_sizes, int n_in,
                              void* d_out, int out_size, void* d_ws, size_t ws_size,
                              hipStream_t stream) {
  const float* x = (const float*)d_in[0];
  const float* gn_gamma = (const float*)d_in[1];
  const float* gn_beta = (const float*)d_in[2];
  const float* hp_weight = (const float*)d_in[3];
  const float* dir_w = (const float*)d_in[4];
  const float* dir_b = (const float*)d_in[5];
  const float* mag_w = (const float*)d_in[6];
  const float* mag_b = (const float*)d_in[7];
  const float* hfg_w = (const float*)d_in[8];
  const float* hfg_b = (const float*)d_in[9];
  float* out = (float*)d_out;

  // ws layout (floats)
  float* ws = (float*)d_ws;
  float* partials = ws;                       // 2048
  float* ab = ws + 2048;                      // 1024
  float* xl = ws + 4096;                      // 8388608
  float* hfl = xl + (size_t)B_ * C_ * HL_ * WL_;   // 8388608
  float2* grid = (float2*)(hfl + (size_t)B_ * C_ * HL_ * WL_);  // 1048576 floats

  k1_partial<<<B_ * GN_G * PB, 256, 0, stream>>>(x, partials);
  k1_finish<<<1, 512, 0, stream>>>(partials, gn_gamma, gn_beta, ab);
  k2_pool<<<(B_ * C_ * HL_ * WL_) / 256, 256, 0, stream>>>(x, ab, hp_weight, xl, hfl);
  k3_offset<<<(B_ * HL_ * WL_) / 256, 256, 0, stream>>>(xl, hfl, dir_w, dir_b, mag_w,
                                                        mag_b, hfg_w, hfg_b, grid);
  k4_sample<<<(B_ * C_ * HL_ * WL_) / 256, 256, 0, stream>>>(x, grid, out);
}